// Round 12
// baseline (301.826 us; speedup 1.0000x reference)
//
#include <hip/hip_runtime.h>
#include <math.h>

#define Bb 128
#define Tt 1024
#define Ll 96
#define WS_STRIDE 200   // floats per batch in workspace

typedef float v2f __attribute__((ext_vector_type(2)));
typedef float v4f __attribute__((ext_vector_type(4)));

// 256 blocks x 1 wave: block b<128 = FORWARD half-chain of batch b;
// block b+128 = BACKWARD half-chain (bidirectional split, 512 serial steps).
//
// Round-12 changes vs round 11:
//  * combine folded into the scan kernel: fwd publishes {Q_511, Dk_f, ps}
//    to d_ws (relaxed agent atomics) + threadfence + release flag; bwd
//    spin-waits (acquire) and writes out[b]. Deadlock-free: fwd never waits.
//    d_ws zeroed per dispatch via hipMemsetAsync on the stream.
//    Removes the ~50us second-launch + combine overhead seen in round 11.
//  * full 24-quad bottom preload: ALL state reads issue at the bottom right
//    after the ds_write (same-wave DS ordering -> single buffer is correct);
//    loop top is pure register FMAs. Bookkeeping + backedge cover the
//    read-train latency.
__global__ __launch_bounds__(64, 1)
__attribute__((amdgpu_waves_per_eu(1)))
void crf_scan_kernel(
    const float* __restrict__ inputs,      // (B, T, L) fp32
    const int*   __restrict__ labels_idx,  // (B, T) int32
    const float* __restrict__ trans,       // (L, L) fp32
    float*       __restrict__ ws,          // workspace: 128 x WS_STRIDE floats
    float*       __restrict__ out)         // (B, 1) fp32
{
    const int blk = blockIdx.x;
    const bool fw = (blk < Bb);
    const int b   = fw ? blk : (blk - Bb);
    const int i   = threadIdx.x;                     // 0..63
    const int col = (2 * i < Ll) ? 2 * i : (Ll - 2); // clamp lanes 48..63

    __shared__ __align__(16) float buf[Ll];          // single state buffer

    const float* xbase = inputs + (size_t)b * Tt * Ll;
    float* wsb = ws + (size_t)b * WS_STRIDE;
    unsigned* wsu = reinterpret_cast<unsigned*>(wsb);

#define EPAIRS(X) \
    X(0)  X(1)  X(2)  X(3)  X(4)  X(5)  X(6)  X(7)  X(8)  X(9)  X(10) X(11) \
    X(12) X(13) X(14) X(15) X(16) X(17) X(18) X(19) X(20) X(21) X(22) X(23) \
    X(24) X(25) X(26) X(27) X(28) X(29) X(30) X(31) X(32) X(33) X(34) X(35) \
    X(36) X(37) X(38) X(39) X(40) X(41) X(42) X(43) X(44) X(45) X(46) X(47)

#define EDECL(p) v2f EA##p, EB##p;

// one quad: 4 pk-FMAs; q-pairs {x,y}/{z,w} are adjacent VGPRs (no splat).
// acc0/acc1 -> output column col; acc2/acc3 -> column col+1.
#define CHUNK(q4, p0, p1) { \
        acc0 += (v2f){q4.x, q4.y} * EA##p0; \
        acc1 += (v2f){q4.z, q4.w} * EA##p1; \
        acc2 += (v2f){q4.x, q4.y} * EB##p0; \
        acc3 += (v2f){q4.z, q4.w} * EB##p1; }

#define MATVEC_ALLP \
        CHUNK(P0,  0,  1)   CHUNK(P1,  2,  3)  \
        CHUNK(P2,  4,  5)   CHUNK(P3,  6,  7)  \
        CHUNK(P4,  8,  9)   CHUNK(P5,  10, 11) \
        CHUNK(P6,  12, 13)  CHUNK(P7,  14, 15) \
        CHUNK(P8,  16, 17)  CHUNK(P9,  18, 19) \
        CHUNK(P10, 20, 21)  CHUNK(P11, 22, 23) \
        CHUNK(P12, 24, 25)  CHUNK(P13, 26, 27) \
        CHUNK(P14, 28, 29)  CHUNK(P15, 30, 31) \
        CHUNK(P16, 32, 33)  CHUNK(P17, 34, 35) \
        CHUNK(P18, 36, 37)  CHUNK(P19, 38, 39) \
        CHUNK(P20, 40, 41)  CHUNK(P21, 42, 43) \
        CHUNK(P22, 44, 45)  CHUNK(P23, 46, 47)

#define PRELOAD(src) { const v4f* qn_ = reinterpret_cast<const v4f*>(src); \
        P0  = qn_[0];  P1  = qn_[1];  P2  = qn_[2];  P3  = qn_[3];  \
        P4  = qn_[4];  P5  = qn_[5];  P6  = qn_[6];  P7  = qn_[7];  \
        P8  = qn_[8];  P9  = qn_[9];  P10 = qn_[10]; P11 = qn_[11]; \
        P12 = qn_[12]; P13 = qn_[13]; P14 = qn_[14]; P15 = qn_[15]; \
        P16 = qn_[16]; P17 = qn_[17]; P18 = qn_[18]; P19 = qn_[19]; \
        P20 = qn_[20]; P21 = qn_[21]; P22 = qn_[22]; P23 = qn_[23]; }

    v4f P0,P1,P2,P3,P4,P5,P6,P7,P8,P9,P10,P11,
        P12,P13,P14,P15,P16,P17,P18,P19,P20,P21,P22,P23;

    if (fw) {
        // ================= FORWARD: t = 1..511 =================
        float ps = 0.f;
        {
            const int* lb = labels_idx + b * Tt;
            #pragma unroll 4
            for (int t = i; t < Tt; t += 64) {
                int i0 = lb[t];
                ps += xbase[t * Ll + i0];
                if (t < Tt - 1) ps += trans[i0 * Ll + lb[t + 1]];
            }
            #pragma unroll
            for (int off = 32; off; off >>= 1) ps += __shfl_xor(ps, off, 64);
        }

        EPAIRS(EDECL)
        // column pairs: EA_p = {E[2p][col], E[2p+1][col]}, EB_p same col+1
#define EINIT(p) { \
        v2f r0 = *reinterpret_cast<const v2f*>(&trans[(2*(p))     * Ll + col]); \
        v2f r1 = *reinterpret_cast<const v2f*>(&trans[(2*(p) + 1) * Ll + col]); \
        EA##p = (v2f){__expf(r0.x), __expf(r1.x)}; \
        EB##p = (v2f){__expf(r0.y), __expf(r1.y)}; \
        asm volatile("" ::: "memory"); }
        EPAIRS(EINIT)
#undef EINIT

        v2f x0 = *reinterpret_cast<const v2f*>(&xbase[col]);
        v2f qv = (v2f){__expf(x0.x), __expf(x0.y)};
        if (i < 48) *reinterpret_cast<v2f*>(&buf[col]) = qv;
        asm volatile("" ::: "memory");
        PRELOAD(buf)

        v2f x1 = *reinterpret_cast<const v2f*>(&xbase[1 * Ll + col]);
        v2f ew = (v2f){__expf(x1.x), __expf(x1.y)};
        v2f x2 = *reinterpret_cast<const v2f*>(&xbase[2 * Ll + col]);
        v2f x3 = *reinterpret_cast<const v2f*>(&xbase[3 * Ll + col]);
        v2f x4 = *reinterpret_cast<const v2f*>(&xbase[4 * Ll + col]);
        v2f x5 = *reinterpret_cast<const v2f*>(&xbase[5 * Ll + col]);
        v2f x6 = *reinterpret_cast<const v2f*>(&xbase[6 * Ll + col]);
        v2f x7 = *reinterpret_cast<const v2f*>(&xbase[7 * Ll + col]);

        int Dk = 0;
        #pragma unroll 1
        for (int t = 1; t <= Tt / 2 - 1; ++t) {
            int k = ((__float_as_int(P0.x) >> 23) & 0xff) - 127;  // wave-uniform
            Dk += k;
            float r = __uint_as_float((unsigned)(127 - k) << 23); // exact 2^-k
            v2f w = ew * r;

            v2f acc0 = {0.f,0.f}, acc1 = {0.f,0.f};
            v2f acc2 = {0.f,0.f}, acc3 = {0.f,0.f};
            MATVEC_ALLP
            v2f va = acc0 + acc1, vb = acc2 + acc3;
            qv = (v2f){va.x + va.y, vb.x + vb.y} * w;

            if (i < 48) *reinterpret_cast<v2f*>(&buf[col]) = qv;
            asm volatile("" ::: "memory");
            PRELOAD(buf)           // in-order DS pipe: sees the new state

            // off-path bookkeeping (overlaps the read-train latency)
            ew = (v2f){__expf(x2.x), __expf(x2.y)};
            x2 = x3; x3 = x4; x4 = x5; x5 = x6; x6 = x7;
            int row = t + 7; if (row > Tt - 1) row = Tt - 1;
            x7 = *reinterpret_cast<const v2f*>(&xbase[row * Ll + col]);
        }

        // ---- publish {Q_511, Dk, ps} then release the flag ----
        if (i < 48) {
            __hip_atomic_store(&wsu[col],     __float_as_uint(qv.x),
                               __ATOMIC_RELAXED, __HIP_MEMORY_SCOPE_AGENT);
            __hip_atomic_store(&wsu[col + 1], __float_as_uint(qv.y),
                               __ATOMIC_RELAXED, __HIP_MEMORY_SCOPE_AGENT);
        }
        if (i == 0) {
            __hip_atomic_store(&wsu[192], (unsigned)Dk,
                               __ATOMIC_RELAXED, __HIP_MEMORY_SCOPE_AGENT);
            __hip_atomic_store(&wsu[194], __float_as_uint(ps),
                               __ATOMIC_RELAXED, __HIP_MEMORY_SCOPE_AGENT);
        }
        __threadfence();   // drain all lanes' stores, device scope
        if (i == 0)
            __hip_atomic_store(&wsu[196], 1u,
                               __ATOMIC_RELEASE, __HIP_MEMORY_SCOPE_AGENT);
    } else {
        // ================= BACKWARD: t = 1023..512 =================
        EPAIRS(EDECL)
        // row pairs (contiguous loads): EA_p = {E[col][2p], E[col][2p+1]}
#define EINIT(p) { \
        v2f r0 = *reinterpret_cast<const v2f*>(&trans[col       * Ll + 2*(p)]); \
        v2f r1 = *reinterpret_cast<const v2f*>(&trans[(col + 1) * Ll + 2*(p)]); \
        EA##p = (v2f){__expf(r0.x), __expf(r0.y)}; \
        EB##p = (v2f){__expf(r1.x), __expf(r1.y)}; \
        asm volatile("" ::: "memory"); }
        EPAIRS(EINIT)
#undef EINIT

        // s_1023 = exp(x_1023)
        v2f xT = *reinterpret_cast<const v2f*>(&xbase[(Tt - 1) * Ll + col]);
        v2f s0 = (v2f){__expf(xT.x), __expf(xT.y)};
        if (i < 48) *reinterpret_cast<v2f*>(&buf[col]) = s0;
        asm volatile("" ::: "memory");
        PRELOAD(buf)

        v2f xh = *reinterpret_cast<const v2f*>(&xbase[(Tt - 2) * Ll + col]);
        v2f ew = (v2f){__expf(xh.x), __expf(xh.y)};
        v2f x2 = *reinterpret_cast<const v2f*>(&xbase[(Tt - 3) * Ll + col]);
        v2f x3 = *reinterpret_cast<const v2f*>(&xbase[(Tt - 4) * Ll + col]);
        v2f x4 = *reinterpret_cast<const v2f*>(&xbase[(Tt - 5) * Ll + col]);
        v2f x5 = *reinterpret_cast<const v2f*>(&xbase[(Tt - 6) * Ll + col]);
        v2f x6 = *reinterpret_cast<const v2f*>(&xbase[(Tt - 7) * Ll + col]);
        v2f x7 = *reinterpret_cast<const v2f*>(&xbase[(Tt - 8) * Ll + col]);

        int Dk = 0, k = 0;
        v2f qv = (v2f){0.f, 0.f};
        #pragma unroll 1
        for (int t = Tt - 1; t >= Tt / 2; --t) {
            k = ((__float_as_int(P0.x) >> 23) & 0xff) - 127;    // from s_t[0]
            Dk += k;
            float r = __uint_as_float((unsigned)(127 - k) << 23);

            v2f acc0 = {0.f,0.f}, acc1 = {0.f,0.f};
            v2f acc2 = {0.f,0.f}, acc3 = {0.f,0.f};
            MATVEC_ALLP
            v2f va = acc0 + acc1, vb = acc2 + acc3;
            qv = (v2f){va.x + va.y, vb.x + vb.y};   // V_{t-1} (stored scale)

            v2f sw = qv * (ew * r);                 // s_{t-1}
            if (i < 48) *reinterpret_cast<v2f*>(&buf[col]) = sw;
            asm volatile("" ::: "memory");
            PRELOAD(buf)

            ew = (v2f){__expf(x2.x), __expf(x2.y)};
            x2 = x3; x3 = x4; x4 = x5; x5 = x6; x6 = x7;
            int row = t - 8; if (row < 0) row = 0;
            x7 = *reinterpret_cast<const v2f*>(&xbase[row * Ll + col]);
        }
        Dk -= k;   // last k applied only to the never-consumed s_511 write

        // ---- wait for forward's publication, then finish out[b] ----
        while (__hip_atomic_load(&wsu[196], __ATOMIC_ACQUIRE,
                                 __HIP_MEMORY_SCOPE_AGENT) == 0) {
            __builtin_amdgcn_s_sleep(4);
        }
        float d = 0.f;
        if (i < 48) {
            float Qx = __uint_as_float(__hip_atomic_load(&wsu[col],
                           __ATOMIC_RELAXED, __HIP_MEMORY_SCOPE_AGENT));
            float Qy = __uint_as_float(__hip_atomic_load(&wsu[col + 1],
                           __ATOMIC_RELAXED, __HIP_MEMORY_SCOPE_AGENT));
            d = Qx * qv.x + Qy * qv.y;
        }
        #pragma unroll
        for (int off = 32; off; off >>= 1) d += __shfl_xor(d, off, 64);
        if (i == 0) {
            int Dkf = (int)__hip_atomic_load(&wsu[192], __ATOMIC_RELAXED,
                                             __HIP_MEMORY_SCOPE_AGENT);
            float psv = __uint_as_float(__hip_atomic_load(&wsu[194],
                            __ATOMIC_RELAXED, __HIP_MEMORY_SCOPE_AGENT));
            double ln = (double)(Dkf + Dk) * 0.6931471805599453 + log((double)d);
            out[b] = (float)(ln - (double)psv);
        }
    }
#undef PRELOAD
#undef MATVEC_ALLP
#undef CHUNK
#undef EDECL
#undef EPAIRS
}

extern "C" void kernel_launch(void* const* d_in, const int* in_sizes, int n_in,
                              void* d_out, int out_size, void* d_ws, size_t ws_size,
                              hipStream_t stream) {
    const float* inputs     = (const float*)d_in[0];
    const int*   labels_idx = (const int*)d_in[1];
    const float* trans      = (const float*)d_in[2];
    float*       out        = (float*)d_out;
    float*       ws         = (float*)d_ws;

    hipMemsetAsync(d_ws, 0, (size_t)Bb * WS_STRIDE * sizeof(float), stream);
    crf_scan_kernel<<<dim3(2 * Bb), dim3(64), 0, stream>>>(inputs, labels_idx,
                                                           trans, ws, out);
}

// Round 13
// 281.368 us; speedup vs baseline: 1.0727x; 1.0727x over previous
//
#include <hip/hip_runtime.h>
#include <math.h>

#define Bb 128
#define Tt 1024
#define Ll 96
#define WS_STRIDE 200   // floats per batch in workspace

typedef float v2f __attribute__((ext_vector_type(2)));
typedef float v4f __attribute__((ext_vector_type(4)));
typedef int   v2i __attribute__((ext_vector_type(2)));

// Cross-group (lane ^ 32) sum via v_permlane32_swap (VALU pipe, ~4cy - not
// LDS). With both operands = p the two outputs are low-dup and high-dup;
// their sum = p[i&31] + p[i|32] in every lane (robust to half-assignment).
static __device__ __forceinline__ float xadd32(float p) {
#if __has_builtin(__builtin_amdgcn_permlane32_swap)
    v2i rr = __builtin_amdgcn_permlane32_swap(__float_as_int(p),
                                              __float_as_int(p), false, false);
    return __int_as_float(rr.x) + __int_as_float(rr.y);
#else
    return p + __shfl_xor(p, 32, 64);
#endif
}

// 256 blocks x 1 wave: block b<128 = FORWARD half-chain of batch b;
// block b+128 = BACKWARD half-chain (bidirectional split, 512 serial steps).
// Two kernels (round-12 fold was net-negative; harness overhead is ~55us
// fixed regardless of launch count - only scan time matters).
//
// Round-13 step structure (group-split matvec):
//  * lane i: group g=i>>5 covers state elems [48g,48g+48); slot j=i&31 owns
//    output cols {j, j+32, j+64}. Each group reads only ITS half of the
//    state: 12 ds_read_b128 (2 distinct broadcast addrs per instr,
//    bank-disjoint) + 1 b32 k-read  vs 24 reads before.
//  * per lane 72 pk-FMAs (3 cols x 48 elems) vs 96.
//  * cross-group combine: one permlane32_swap + add per col (VALU).
//  * E = 144 floats/lane (3 cols x 48 elems) vs 192: less reg pressure.
__global__ __launch_bounds__(64, 1)
__attribute__((amdgpu_waves_per_eu(1)))
void crf_scan_kernel(
    const float* __restrict__ inputs,      // (B, T, L) fp32
    const int*   __restrict__ labels_idx,  // (B, T) int32
    const float* __restrict__ trans,       // (L, L) fp32
    float*       __restrict__ ws)          // workspace: 128 x WS_STRIDE floats
{
    const int blk = blockIdx.x;
    const bool fw = (blk < Bb);
    const int b   = fw ? blk : (blk - Bb);
    const int i   = threadIdx.x;       // 0..63
    const int g   = i >> 5;            // group: state half [48g, 48g+48)
    const int j   = i & 31;            // slot: owns cols j, j+32, j+64
    const int g48 = g * 48;
    const int cA  = j, cB = j + 32, cC = j + 64;

    __shared__ __align__(16) float buf[Ll];          // single state buffer

    const float* xbase = inputs + (size_t)b * Tt * Ll;
    float* wsb = ws + (size_t)b * WS_STRIDE;

#define EP24(X) \
    X(0)  X(1)  X(2)  X(3)  X(4)  X(5)  X(6)  X(7)  X(8)  X(9)  X(10) X(11) \
    X(12) X(13) X(14) X(15) X(16) X(17) X(18) X(19) X(20) X(21) X(22) X(23)

#define EDECL(p) v2f EA##p, EB##p, EC##p;

// one quad (4 state elems = E-pairs p0,p1): 6 pk-FMAs, operands straight
// from the ds_read_b128 quad (adjacent VGPR pairs, no splats).
#define CHUNK(q, p0, p1) { \
        aA0 += (v2f){P##q.x, P##q.y} * EA##p0; \
        aA1 += (v2f){P##q.z, P##q.w} * EA##p1; \
        aB0 += (v2f){P##q.x, P##q.y} * EB##p0; \
        aB1 += (v2f){P##q.z, P##q.w} * EB##p1; \
        aC0 += (v2f){P##q.x, P##q.y} * EC##p0; \
        aC1 += (v2f){P##q.z, P##q.w} * EC##p1; }

#define MATVEC \
        CHUNK(0, 0, 1)   CHUNK(1, 2, 3)   CHUNK(2, 4, 5)   CHUNK(3, 6, 7)   \
        CHUNK(4, 8, 9)   CHUNK(5, 10,11)  CHUNK(6, 12,13)  CHUNK(7, 14,15)  \
        CHUNK(8, 16,17)  CHUNK(9, 18,19)  CHUNK(10,20,21)  CHUNK(11,22,23)

// read own group's 12 quads (2 distinct broadcast addrs/instr) + k-scalar.
#define PRELOAD { const v4f* qb_ = reinterpret_cast<const v4f*>(buf) + g * 12; \
        P0 = qb_[0]; P1 = qb_[1]; P2  = qb_[2];  P3  = qb_[3];  \
        P4 = qb_[4]; P5 = qb_[5]; P6  = qb_[6];  P7  = qb_[7];  \
        P8 = qb_[8]; P9 = qb_[9]; P10 = qb_[10]; P11 = qb_[11]; \
        Pk = buf[0]; }

    v4f P0,P1,P2,P3,P4,P5,P6,P7,P8,P9,P10,P11;
    float Pk;

    if (fw) {
        // ================= FORWARD: t = 1..511 =================
        float ps = 0.f;
        {
            const int* lb = labels_idx + b * Tt;
            #pragma unroll 4
            for (int t = i; t < Tt; t += 64) {
                int i0 = lb[t];
                ps += xbase[t * Ll + i0];
                if (t < Tt - 1) ps += trans[i0 * Ll + lb[t + 1]];
            }
            #pragma unroll
            for (int off = 32; off; off >>= 1) ps += __shfl_xor(ps, off, 64);
        }

        EP24(EDECL)
        // fwd: out[c] = sum_e E[e][c] q[e]; pairs over e within own half.
#define EINIT(p) { \
        int e0 = (g48 + 2*(p)) * Ll, e1 = (g48 + 2*(p) + 1) * Ll; \
        EA##p = (v2f){__expf(trans[e0 + cA]), __expf(trans[e1 + cA])}; \
        EB##p = (v2f){__expf(trans[e0 + cB]), __expf(trans[e1 + cB])}; \
        EC##p = (v2f){__expf(trans[e0 + cC]), __expf(trans[e1 + cC])}; \
        asm volatile("" ::: "memory"); }
        EP24(EINIT)
#undef EINIT

        // q_0 = exp(x_0)
        float qA = __expf(xbase[cA]);
        float qB = __expf(xbase[cB]);
        float qC = __expf(xbase[cC]);
        if (i < 32) { buf[cA] = qA; buf[cB] = qB; buf[cC] = qC; }
        asm volatile("" ::: "memory");
        PRELOAD

        // x queue: ew* = exp(row t); x2..x7 = rows t+1..t+6
        float ewA = __expf(xbase[1 * Ll + cA]);
        float ewB = __expf(xbase[1 * Ll + cB]);
        float ewC = __expf(xbase[1 * Ll + cC]);
        float x2A = xbase[2*Ll+cA], x2B = xbase[2*Ll+cB], x2C = xbase[2*Ll+cC];
        float x3A = xbase[3*Ll+cA], x3B = xbase[3*Ll+cB], x3C = xbase[3*Ll+cC];
        float x4A = xbase[4*Ll+cA], x4B = xbase[4*Ll+cB], x4C = xbase[4*Ll+cC];
        float x5A = xbase[5*Ll+cA], x5B = xbase[5*Ll+cB], x5C = xbase[5*Ll+cC];
        float x6A = xbase[6*Ll+cA], x6B = xbase[6*Ll+cB], x6C = xbase[6*Ll+cC];
        float x7A = xbase[7*Ll+cA], x7B = xbase[7*Ll+cB], x7C = xbase[7*Ll+cC];

        int Dk = 0;
        #pragma unroll 1
        for (int t = 1; t <= Tt / 2 - 1; ++t) {
            int k = ((__float_as_int(Pk) >> 23) & 0xff) - 127;  // wave-uniform
            Dk += k;
            float r = __uint_as_float((unsigned)(127 - k) << 23); // exact 2^-k
            float wA = ewA * r, wB = ewB * r, wC = ewC * r;

            v2f aA0 = {0.f,0.f}, aA1 = {0.f,0.f};
            v2f aB0 = {0.f,0.f}, aB1 = {0.f,0.f};
            v2f aC0 = {0.f,0.f}, aC1 = {0.f,0.f};
            MATVEC
            v2f tA = aA0 + aA1, tB = aB0 + aB1, tC = aC0 + aC1;
            qA = xadd32(tA.x + tA.y) * wA;
            qB = xadd32(tB.x + tB.y) * wB;
            qC = xadd32(tC.x + tC.y) * wC;

            if (i < 32) { buf[cA] = qA; buf[cB] = qB; buf[cC] = qC; }
            asm volatile("" ::: "memory");
            PRELOAD   // in-order same-wave DS: sees the new state

            // off-path bookkeeping (overlaps the read-train latency)
            ewA = __expf(x2A); ewB = __expf(x2B); ewC = __expf(x2C);
            x2A = x3A; x2B = x3B; x2C = x3C;
            x3A = x4A; x3B = x4B; x3C = x4C;
            x4A = x5A; x4B = x5B; x4C = x5C;
            x5A = x6A; x5B = x6B; x5C = x6C;
            x6A = x7A; x6B = x7B; x6C = x7C;
            int row = t + 7; if (row > Tt - 1) row = Tt - 1;
            x7A = xbase[row*Ll+cA]; x7B = xbase[row*Ll+cB]; x7C = xbase[row*Ll+cC];
        }
        if (i < 32) { wsb[cA] = qA; wsb[cB] = qB; wsb[cC] = qC; }   // Q_511
        if (i == 0) { wsb[192] = __int_as_float(Dk); wsb[194] = ps; }
    } else {
        // ================= BACKWARD: t = 1023..512 =================
        EP24(EDECL)
        // bwd: out[c] = sum_e E[c][e] s[e]; pairs over e are CONTIGUOUS.
#define EINIT(p) { \
        v2f rA = *reinterpret_cast<const v2f*>(&trans[cA * Ll + g48 + 2*(p)]); \
        v2f rB = *reinterpret_cast<const v2f*>(&trans[cB * Ll + g48 + 2*(p)]); \
        v2f rC = *reinterpret_cast<const v2f*>(&trans[cC * Ll + g48 + 2*(p)]); \
        EA##p = (v2f){__expf(rA.x), __expf(rA.y)}; \
        EB##p = (v2f){__expf(rB.x), __expf(rB.y)}; \
        EC##p = (v2f){__expf(rC.x), __expf(rC.y)}; \
        asm volatile("" ::: "memory"); }
        EP24(EINIT)
#undef EINIT

        // s_1023 = exp(x_1023)
        float sA = __expf(xbase[(Tt-1)*Ll + cA]);
        float sB = __expf(xbase[(Tt-1)*Ll + cB]);
        float sC = __expf(xbase[(Tt-1)*Ll + cC]);
        if (i < 32) { buf[cA] = sA; buf[cB] = sB; buf[cC] = sC; }
        asm volatile("" ::: "memory");
        PRELOAD

        // queue: ew* = exp(row t-1); x2..x7 = rows t-2..t-7
        float ewA = __expf(xbase[(Tt-2)*Ll + cA]);
        float ewB = __expf(xbase[(Tt-2)*Ll + cB]);
        float ewC = __expf(xbase[(Tt-2)*Ll + cC]);
        float x2A = xbase[(Tt-3)*Ll+cA], x2B = xbase[(Tt-3)*Ll+cB], x2C = xbase[(Tt-3)*Ll+cC];
        float x3A = xbase[(Tt-4)*Ll+cA], x3B = xbase[(Tt-4)*Ll+cB], x3C = xbase[(Tt-4)*Ll+cC];
        float x4A = xbase[(Tt-5)*Ll+cA], x4B = xbase[(Tt-5)*Ll+cB], x4C = xbase[(Tt-5)*Ll+cC];
        float x5A = xbase[(Tt-6)*Ll+cA], x5B = xbase[(Tt-6)*Ll+cB], x5C = xbase[(Tt-6)*Ll+cC];
        float x6A = xbase[(Tt-7)*Ll+cA], x6B = xbase[(Tt-7)*Ll+cB], x6C = xbase[(Tt-7)*Ll+cC];
        float x7A = xbase[(Tt-8)*Ll+cA], x7B = xbase[(Tt-8)*Ll+cB], x7C = xbase[(Tt-8)*Ll+cC];

        int Dk = 0, k = 0;
        float VA = 0.f, VB = 0.f, VC = 0.f;
        #pragma unroll 1
        for (int t = Tt - 1; t >= Tt / 2; --t) {
            k = ((__float_as_int(Pk) >> 23) & 0xff) - 127;      // from s_t[0]
            Dk += k;
            float r = __uint_as_float((unsigned)(127 - k) << 23);

            v2f aA0 = {0.f,0.f}, aA1 = {0.f,0.f};
            v2f aB0 = {0.f,0.f}, aB1 = {0.f,0.f};
            v2f aC0 = {0.f,0.f}, aC1 = {0.f,0.f};
            MATVEC
            v2f tA = aA0 + aA1, tB = aB0 + aB1, tC = aC0 + aC1;
            VA = xadd32(tA.x + tA.y);           // V_{t-1} (stored scale)
            VB = xadd32(tB.x + tB.y);
            VC = xadd32(tC.x + tC.y);

            float swA = VA * (ewA * r);         // s_{t-1}
            float swB = VB * (ewB * r);
            float swC = VC * (ewC * r);
            if (i < 32) { buf[cA] = swA; buf[cB] = swB; buf[cC] = swC; }
            asm volatile("" ::: "memory");
            PRELOAD

            ewA = __expf(x2A); ewB = __expf(x2B); ewC = __expf(x2C);
            x2A = x3A; x2B = x3B; x2C = x3C;
            x3A = x4A; x3B = x4B; x3C = x4C;
            x4A = x5A; x4B = x5B; x4C = x5C;
            x5A = x6A; x5B = x6B; x5C = x6C;
            x6A = x7A; x6B = x7B; x6C = x7C;
            int row = t - 8; if (row < 0) row = 0;
            x7A = xbase[row*Ll+cA]; x7B = xbase[row*Ll+cB]; x7C = xbase[row*Ll+cC];
        }
        Dk -= k;   // last k applied only to the never-consumed s_511 write
        if (i < 32) { wsb[96+cA] = VA; wsb[96+cB] = VB; wsb[96+cC] = VC; } // V_511
        if (i == 0) wsb[193] = __int_as_float(Dk);
    }
#undef PRELOAD
#undef MATVEC
#undef CHUNK
#undef EDECL
#undef EP24
}

// meeting point: log_norm = log(V_511 . Q_511) + (Dk_f + Dk_b)*ln2
__global__ __launch_bounds__(64, 1) void crf_combine_kernel(
    const float* __restrict__ ws, float* __restrict__ out)
{
    const int b = blockIdx.x;
    const int i = threadIdx.x;
    const int col = (2 * i < Ll) ? 2 * i : (Ll - 2);
    const float* wsb = ws + (size_t)b * WS_STRIDE;

    float d = 0.f;
    if (i < 48) {
        v2f Q = *reinterpret_cast<const v2f*>(&wsb[col]);
        v2f V = *reinterpret_cast<const v2f*>(&wsb[96 + col]);
        d = Q.x * V.x + Q.y * V.y;
    }
    #pragma unroll
    for (int off = 32; off; off >>= 1) d += __shfl_xor(d, off, 64);
    if (i == 0) {
        int Dkf = __float_as_int(wsb[192]);
        int Dkb = __float_as_int(wsb[193]);
        float ps = wsb[194];
        double ln = (double)(Dkf + Dkb) * 0.6931471805599453 + log((double)d);
        out[b] = (float)(ln - (double)ps);
    }
}

extern "C" void kernel_launch(void* const* d_in, const int* in_sizes, int n_in,
                              void* d_out, int out_size, void* d_ws, size_t ws_size,
                              hipStream_t stream) {
    const float* inputs     = (const float*)d_in[0];
    const int*   labels_idx = (const int*)d_in[1];
    const float* trans      = (const float*)d_in[2];
    float*       out        = (float*)d_out;
    float*       ws         = (float*)d_ws;

    crf_scan_kernel<<<dim3(2 * Bb), dim3(64), 0, stream>>>(inputs, labels_idx, trans, ws);
    crf_combine_kernel<<<dim3(Bb), dim3(64), 0, stream>>>(ws, out);
}

// Round 14
// 173.712 us; speedup vs baseline: 1.7375x; 1.6197x over previous
//
#include <hip/hip_runtime.h>
#include <math.h>

#define Bb 128
#define Tt 1024
#define Ll 96
#define NSEG 8
#define WS_STRIDE 1408
#define CUT(s) (1 + ((Tt - 1) * (s)) / NSEG)

typedef float v2f __attribute__((ext_vector_type(2)));
typedef float v4f __attribute__((ext_vector_type(4)));
typedef int   v2i __attribute__((ext_vector_type(2)));

// Cross-group (lane ^ 32) sum via v_permlane32_swap (VALU pipe, not LDS).
static __device__ __forceinline__ float xadd32(float p) {
#if __has_builtin(__builtin_amdgcn_permlane32_swap)
    v2i rr = __builtin_amdgcn_permlane32_swap(__float_as_int(p),
                                              __float_as_int(p), false, false);
    return __int_as_float(rr.x) + __int_as_float(rr.y);
#else
    return p + __shfl_xor(p, 32, 64);
#endif
}

// PARALLEL-IN-TIME rank-1 segmentation (round 14). M_t = diag(w_t) E^T are
// strictly positive -> Birkhoff contraction ~tanh(diam(E)/4) ~ 0.2-0.4 per
// step, so a 128-step segment product P_s is rank-1 to ~1e-50:
//   P_s ~= a_s b_s^T / gamma_s,  a_s = P_s y_s (fwd chain, y = exp(x_{lo-1})),
//   b_s^T = 1^T P_s (bwd chain),  gamma_s = sum(a_s).
// log Z = sum_{s=2..S} [log(b_s . a_{s-1}) + ln2(Dkb_s + Dkf_{s-1})]
//       - sum_{s=2..S-1} [log(sum a_s) + ln2 Dkf_s]
// (reduces EXACTLY to the verified round-13 formula at S=2; segment 1's
// y = exp(x_0) makes r1 exact). Serial chain: 512 -> 128 steps; 15 blocks
// per batch (7 fwd chains s=1..7, 7 bwd chains s=2..8, 1 score block).
// Per-step machinery = round 13 verbatim (group-split matvec, 13 broadcast
// ds_read_b128, 72 pk-FMA, permlane32 combine, exponent-field rescale).
__global__ __launch_bounds__(64, 1)
void crf_scan_kernel(
    const float* __restrict__ inputs,      // (B, T, L) fp32
    const int*   __restrict__ labels_idx,  // (B, T) int32
    const float* __restrict__ trans,       // (L, L) fp32
    float*       __restrict__ ws)          // 128 x WS_STRIDE floats
{
    const int cid = blockIdx.x / Bb;       // chain id 0..14
    const int b   = blockIdx.x % Bb;
    const int i   = threadIdx.x;           // 0..63

    const float* xbase = inputs + (size_t)b * Tt * Ll;
    float* wsb = ws + (size_t)b * WS_STRIDE;
    int*   wsi = reinterpret_cast<int*>(wsb);

    if (cid == 2 * (NSEG - 1)) {
        // ================= SCORES =================
        float ps = 0.f;
        const int* lb = labels_idx + b * Tt;
        #pragma unroll 4
        for (int t = i; t < Tt; t += 64) {
            int i0 = lb[t];
            ps += xbase[t * Ll + i0];
            if (t < Tt - 1) ps += trans[i0 * Ll + lb[t + 1]];
        }
        #pragma unroll
        for (int off = 32; off; off >>= 1) ps += __shfl_xor(ps, off, 64);
        if (i == 0) wsb[1364] = ps;
        return;
    }

    const bool fw = (cid < NSEG - 1);
    const int  s  = fw ? (cid + 1) : (cid - NSEG + 3);  // fwd s=1..7, bwd s=2..8
    const int  lo = CUT(s - 1), hi = CUT(s);            // t-range [lo, hi)

    const int g   = i >> 5;            // group: state half [48g, 48g+48)
    const int j   = i & 31;            // slot: owns cols j, j+32, j+64
    const int g48 = g * 48;
    const int cA  = j, cB = j + 32, cC = j + 64;

    __shared__ __align__(16) float buf[Ll];

#define EP24(X) \
    X(0)  X(1)  X(2)  X(3)  X(4)  X(5)  X(6)  X(7)  X(8)  X(9)  X(10) X(11) \
    X(12) X(13) X(14) X(15) X(16) X(17) X(18) X(19) X(20) X(21) X(22) X(23)

#define EDECL(p) v2f EA##p, EB##p, EC##p;

#define CHUNK(q, p0, p1) { \
        aA0 += (v2f){P##q.x, P##q.y} * EA##p0; \
        aA1 += (v2f){P##q.z, P##q.w} * EA##p1; \
        aB0 += (v2f){P##q.x, P##q.y} * EB##p0; \
        aB1 += (v2f){P##q.z, P##q.w} * EB##p1; \
        aC0 += (v2f){P##q.x, P##q.y} * EC##p0; \
        aC1 += (v2f){P##q.z, P##q.w} * EC##p1; }

#define MATVEC \
        CHUNK(0, 0, 1)   CHUNK(1, 2, 3)   CHUNK(2, 4, 5)   CHUNK(3, 6, 7)   \
        CHUNK(4, 8, 9)   CHUNK(5, 10,11)  CHUNK(6, 12,13)  CHUNK(7, 14,15)  \
        CHUNK(8, 16,17)  CHUNK(9, 18,19)  CHUNK(10,20,21)  CHUNK(11,22,23)

#define PRELOAD { const v4f* qb_ = reinterpret_cast<const v4f*>(buf) + g * 12; \
        P0 = qb_[0]; P1 = qb_[1]; P2  = qb_[2];  P3  = qb_[3];  \
        P4 = qb_[4]; P5 = qb_[5]; P6  = qb_[6];  P7  = qb_[7];  \
        P8 = qb_[8]; P9 = qb_[9]; P10 = qb_[10]; P11 = qb_[11]; \
        Pk = buf[0]; }

    v4f P0,P1,P2,P3,P4,P5,P6,P7,P8,P9,P10,P11;
    float Pk;

    if (fw) {
        // ================= FORWARD chain: a_s = P_s y, y = exp(x_{lo-1}) ====
        EP24(EDECL)
#define EINIT(p) { \
        int e0 = (g48 + 2*(p)) * Ll, e1 = (g48 + 2*(p) + 1) * Ll; \
        EA##p = (v2f){__expf(trans[e0 + cA]), __expf(trans[e1 + cA])}; \
        EB##p = (v2f){__expf(trans[e0 + cB]), __expf(trans[e1 + cB])}; \
        EC##p = (v2f){__expf(trans[e0 + cC]), __expf(trans[e1 + cC])}; \
        asm volatile("" ::: "memory"); }
        EP24(EINIT)
#undef EINIT

        float qA = __expf(xbase[(lo - 1) * Ll + cA]);
        float qB = __expf(xbase[(lo - 1) * Ll + cB]);
        float qC = __expf(xbase[(lo - 1) * Ll + cC]);
        if (i < 32) { buf[cA] = qA; buf[cB] = qB; buf[cC] = qC; }
        asm volatile("" ::: "memory");
        PRELOAD

        float ewA = __expf(xbase[lo * Ll + cA]);
        float ewB = __expf(xbase[lo * Ll + cB]);
        float ewC = __expf(xbase[lo * Ll + cC]);
#define ROWF(d) ((lo + (d) > Tt - 1) ? (Tt - 1) : (lo + (d)))
        float x2A = xbase[ROWF(1)*Ll+cA], x2B = xbase[ROWF(1)*Ll+cB], x2C = xbase[ROWF(1)*Ll+cC];
        float x3A = xbase[ROWF(2)*Ll+cA], x3B = xbase[ROWF(2)*Ll+cB], x3C = xbase[ROWF(2)*Ll+cC];
        float x4A = xbase[ROWF(3)*Ll+cA], x4B = xbase[ROWF(3)*Ll+cB], x4C = xbase[ROWF(3)*Ll+cC];
        float x5A = xbase[ROWF(4)*Ll+cA], x5B = xbase[ROWF(4)*Ll+cB], x5C = xbase[ROWF(4)*Ll+cC];
        float x6A = xbase[ROWF(5)*Ll+cA], x6B = xbase[ROWF(5)*Ll+cB], x6C = xbase[ROWF(5)*Ll+cC];
        float x7A = xbase[ROWF(6)*Ll+cA], x7B = xbase[ROWF(6)*Ll+cB], x7C = xbase[ROWF(6)*Ll+cC];
#undef ROWF

        int Dk = 0;
        #pragma unroll 1
        for (int t = lo; t < hi; ++t) {
            int k = ((__float_as_int(Pk) >> 23) & 0xff) - 127;
            Dk += k;
            float r = __uint_as_float((unsigned)(127 - k) << 23); // exact 2^-k
            float wA = ewA * r, wB = ewB * r, wC = ewC * r;

            v2f aA0 = {0.f,0.f}, aA1 = {0.f,0.f};
            v2f aB0 = {0.f,0.f}, aB1 = {0.f,0.f};
            v2f aC0 = {0.f,0.f}, aC1 = {0.f,0.f};
            MATVEC
            v2f tA = aA0 + aA1, tB = aB0 + aB1, tC = aC0 + aC1;
            qA = xadd32(tA.x + tA.y) * wA;
            qB = xadd32(tB.x + tB.y) * wB;
            qC = xadd32(tC.x + tC.y) * wC;

            if (i < 32) { buf[cA] = qA; buf[cB] = qB; buf[cC] = qC; }
            asm volatile("" ::: "memory");
            PRELOAD

            ewA = __expf(x2A); ewB = __expf(x2B); ewC = __expf(x2C);
            x2A = x3A; x2B = x3B; x2C = x3C;
            x3A = x4A; x3B = x4B; x3C = x4C;
            x4A = x5A; x4B = x5B; x4C = x5C;
            x5A = x6A; x5B = x6B; x5C = x6C;
            x6A = x7A; x6B = x7B; x6C = x7C;
            int row = t + 7; if (row > Tt - 1) row = Tt - 1;
            x7A = xbase[row*Ll+cA]; x7B = xbase[row*Ll+cB]; x7C = xbase[row*Ll+cC];
        }
        if (i < 32) {
            float* dst = wsb + (s - 1) * 96;
            dst[cA] = qA; dst[cB] = qB; dst[cC] = qC;
        }
        if (i == 0) wsi[1344 + (s - 1)] = Dk;
    } else {
        // ================= BACKWARD chain: b_s^T = 1^T P_s =================
        EP24(EDECL)
#define EINIT(p) { \
        v2f rA = *reinterpret_cast<const v2f*>(&trans[cA * Ll + g48 + 2*(p)]); \
        v2f rB = *reinterpret_cast<const v2f*>(&trans[cB * Ll + g48 + 2*(p)]); \
        v2f rC = *reinterpret_cast<const v2f*>(&trans[cC * Ll + g48 + 2*(p)]); \
        EA##p = (v2f){__expf(rA.x), __expf(rA.y)}; \
        EB##p = (v2f){__expf(rB.x), __expf(rB.y)}; \
        EC##p = (v2f){__expf(rC.x), __expf(rC.y)}; \
        asm volatile("" ::: "memory"); }
        EP24(EINIT)
#undef EINIT

        // s_{hi-1} = 1 o w_{hi-1} = exp(x_{hi-1})
        float sA = __expf(xbase[(hi-1)*Ll + cA]);
        float sB = __expf(xbase[(hi-1)*Ll + cB]);
        float sC = __expf(xbase[(hi-1)*Ll + cC]);
        if (i < 32) { buf[cA] = sA; buf[cB] = sB; buf[cC] = sC; }
        asm volatile("" ::: "memory");
        PRELOAD

        float ewA = __expf(xbase[(hi-2)*Ll + cA]);
        float ewB = __expf(xbase[(hi-2)*Ll + cB]);
        float ewC = __expf(xbase[(hi-2)*Ll + cC]);
#define ROWB(d) ((hi - (d) < 0) ? 0 : (hi - (d)))
        float x2A = xbase[ROWB(3)*Ll+cA], x2B = xbase[ROWB(3)*Ll+cB], x2C = xbase[ROWB(3)*Ll+cC];
        float x3A = xbase[ROWB(4)*Ll+cA], x3B = xbase[ROWB(4)*Ll+cB], x3C = xbase[ROWB(4)*Ll+cC];
        float x4A = xbase[ROWB(5)*Ll+cA], x4B = xbase[ROWB(5)*Ll+cB], x4C = xbase[ROWB(5)*Ll+cC];
        float x5A = xbase[ROWB(6)*Ll+cA], x5B = xbase[ROWB(6)*Ll+cB], x5C = xbase[ROWB(6)*Ll+cC];
        float x6A = xbase[ROWB(7)*Ll+cA], x6B = xbase[ROWB(7)*Ll+cB], x6C = xbase[ROWB(7)*Ll+cC];
        float x7A = xbase[ROWB(8)*Ll+cA], x7B = xbase[ROWB(8)*Ll+cB], x7C = xbase[ROWB(8)*Ll+cC];
#undef ROWB

        int Dk = 0, k = 0;
        float VA = 0.f, VB = 0.f, VC = 0.f;
        #pragma unroll 1
        for (int t = hi - 1; t >= lo; --t) {
            k = ((__float_as_int(Pk) >> 23) & 0xff) - 127;
            Dk += k;
            float r = __uint_as_float((unsigned)(127 - k) << 23);

            v2f aA0 = {0.f,0.f}, aA1 = {0.f,0.f};
            v2f aB0 = {0.f,0.f}, aB1 = {0.f,0.f};
            v2f aC0 = {0.f,0.f}, aC1 = {0.f,0.f};
            MATVEC
            v2f tA = aA0 + aA1, tB = aB0 + aB1, tC = aC0 + aC1;
            VA = xadd32(tA.x + tA.y);       // v_{t-1} (stored scale)
            VB = xadd32(tB.x + tB.y);
            VC = xadd32(tC.x + tC.y);

            float swA = VA * (ewA * r);     // s_{t-1}
            float swB = VB * (ewB * r);
            float swC = VC * (ewC * r);
            if (i < 32) { buf[cA] = swA; buf[cB] = swB; buf[cC] = swC; }
            asm volatile("" ::: "memory");
            PRELOAD

            ewA = __expf(x2A); ewB = __expf(x2B); ewC = __expf(x2C);
            x2A = x3A; x2B = x3B; x2C = x3C;
            x3A = x4A; x3B = x4B; x3C = x4C;
            x4A = x5A; x4B = x5B; x4C = x5C;
            x5A = x6A; x5B = x6B; x5C = x6C;
            x6A = x7A; x6B = x7B; x6C = x7C;
            int row = t - 8; if (row < 0) row = 0;
            x7A = xbase[row*Ll+cA]; x7B = xbase[row*Ll+cB]; x7C = xbase[row*Ll+cC];
        }
        Dk -= k;   // last k applied only to the never-consumed s_{lo-1} write
        if (i < 32) {
            float* dst = wsb + 672 + (s - 2) * 96;
            dst[cA] = VA; dst[cB] = VB; dst[cC] = VC;
        }
        if (i == 0) wsi[1352 + (s - 2)] = Dk;
    }
#undef PRELOAD
#undef MATVEC
#undef CHUNK
#undef EDECL
#undef EP24
}

// log Z = sum_{s=2..S} [log(b_s . a_{s-1}) + ln2(Dkb_s + Dkf_{s-1})]
//       - sum_{s=2..S-1} [log(sum a_s) + ln2 Dkf_s];  out = log Z - ps
__global__ __launch_bounds__(64, 1) void crf_combine_kernel(
    const float* __restrict__ ws, float* __restrict__ out)
{
    const int b = blockIdx.x;
    const int i = threadIdx.x;
    const float* wsb = ws + (size_t)b * WS_STRIDE;
    const int*   wsi = reinterpret_cast<const int*>(wsb);
    const double LN2 = 0.6931471805599453;

    double acc = 0.0;
    #pragma unroll 1
    for (int s = 2; s <= NSEG; ++s) {
        const float* f  = wsb + (s - 2) * 96;        // fwd_{s-1}
        const float* bv = wsb + 672 + (s - 2) * 96;  // bwd_s
        float pd = 0.f;
        if (i < 32) pd = bv[i]*f[i] + bv[i+32]*f[i+32] + bv[i+64]*f[i+64];
        #pragma unroll
        for (int off = 32; off; off >>= 1) pd += __shfl_xor(pd, off, 64);
        acc += log((double)pd)
             + LN2 * (double)(wsi[1352 + (s - 2)] + wsi[1344 + (s - 2)]);
    }
    #pragma unroll 1
    for (int s = 2; s <= NSEG - 1; ++s) {
        const float* f = wsb + (s - 1) * 96;         // fwd_s
        float pg = 0.f;
        if (i < 32) pg = f[i] + f[i+32] + f[i+64];
        #pragma unroll
        for (int off = 32; off; off >>= 1) pg += __shfl_xor(pg, off, 64);
        acc -= log((double)pg) + LN2 * (double)wsi[1344 + (s - 1)];
    }
    if (i == 0) out[b] = (float)(acc - (double)wsb[1364]);
}

extern "C" void kernel_launch(void* const* d_in, const int* in_sizes, int n_in,
                              void* d_out, int out_size, void* d_ws, size_t ws_size,
                              hipStream_t stream) {
    const float* inputs     = (const float*)d_in[0];
    const int*   labels_idx = (const int*)d_in[1];
    const float* trans      = (const float*)d_in[2];
    float*       out        = (float*)d_out;
    float*       ws         = (float*)d_ws;

    crf_scan_kernel<<<dim3((2 * NSEG - 1) * Bb), dim3(64), 0, stream>>>(
        inputs, labels_idx, trans, ws);
    crf_combine_kernel<<<dim3(Bb), dim3(64), 0, stream>>>(ws, out);
}